// Round 5
// baseline (1096.709 us; speedup 1.0000x reference)
//
#include <hip/hip_runtime.h>
#include <math.h>

// Problem constants (S=8192 tokens, E=64 experts, capacity=256)
#define NTOK 8192
#define NEXP 64
#define CAP  256
#define SEC  (NTOK * NEXP * CAP)   // 134217728 floats per output tensor

typedef float v4f __attribute__((ext_vector_type(4)));

// ---------------------------------------------------------------------------
// Kernel 0: faithful clone of __amd_rocclr_fillBufferAligned (the 6.2 TB/s
// reference on this box: WG=256, VGPR_Count=8 => plain dwordx4 + grid-stride,
// no loads). Zeroes BOTH output tensors as one contiguous 1 GiB range.
// 2048 blocks x 256 threads x 128 iterations, no tail, no branches, no nt.
// ---------------------------------------------------------------------------
#define ZWG 2048
__global__ __launch_bounds__(256) void k_zero(v4f* __restrict__ out) {
    const int NV4    = SEC * 2 / 4;          // 67,108,864 float4 total
    const int stride = ZWG * 256;            // 524,288 threads
    v4f z = {0.0f, 0.0f, 0.0f, 0.0f};
    for (int i = blockIdx.x * 256 + threadIdx.x; i < NV4; i += stride)
        out[i] = z;                          // plain global_store_dwordx4
}

// ---------------------------------------------------------------------------
// Kernel 1: per-token argmax (first-index tie-break) + softmax value at top1.
// One wave (64 lanes) per token row; lane e holds logit for expert e.
// ---------------------------------------------------------------------------
__global__ __launch_bounds__(256) void k_top1(const float* __restrict__ in,
                                              int* __restrict__ top1,
                                              float* __restrict__ val) {
    int wave = threadIdx.x >> 6;
    int lane = threadIdx.x & 63;
    int s = blockIdx.x * 4 + wave;
    float x = in[s * NEXP + lane];

    float bv = x;
    int   bi = lane;
#pragma unroll
    for (int off = 32; off > 0; off >>= 1) {
        float ov = __shfl_xor(bv, off);
        int   oi = __shfl_xor(bi, off);
        if (ov > bv || (ov == bv && oi < bi)) { bv = ov; bi = oi; }
    }
    float ex = expf(x - bv);
#pragma unroll
    for (int off = 32; off > 0; off >>= 1) ex += __shfl_xor(ex, off);

    if (lane == 0) {
        top1[s] = bi;
        val[s]  = 1.0f / ex;   // softmax value at the argmax
    }
}

// ---------------------------------------------------------------------------
// Kernel 2: deterministic per-expert exclusive rank via 6-ballot radix masks,
// fused with the sparse scatter (<=8192 nonzero (val, 1.0f) pairs, ~64 KiB).
// Single block, 16 waves; wave w owns tokens [w*512, w*512+512).
// ---------------------------------------------------------------------------
__global__ __launch_bounds__(1024) void k_rank_scatter(const int* __restrict__ top1,
                                                       const float* __restrict__ val,
                                                       float* __restrict__ outc,
                                                       float* __restrict__ outm) {
    __shared__ int localrank[NTOK];      // 32 KB
    __shared__ int hist[16][64];
    __shared__ int chunkoff[16][64];

    int tid  = threadIdx.x;
    int w    = tid >> 6;
    int lane = tid & 63;
    int base = w * 512;

    int cnt = 0;  // lane l: tokens so far in this chunk routed to expert l
    for (int j0 = 0; j0 < 512; j0 += 64) {
        int e = top1[base + j0 + lane];
        unsigned long long b0 = __ballot((e & 1)  != 0);
        unsigned long long b1 = __ballot((e & 2)  != 0);
        unsigned long long b2 = __ballot((e & 4)  != 0);
        unsigned long long b3 = __ballot((e & 8)  != 0);
        unsigned long long b4 = __ballot((e & 16) != 0);
        unsigned long long b5 = __ballot((e & 32) != 0);
        unsigned long long my =
            ((e & 1)  ? b0 : ~b0) & ((e & 2)  ? b1 : ~b1) &
            ((e & 4)  ? b2 : ~b2) & ((e & 8)  ? b3 : ~b3) &
            ((e & 16) ? b4 : ~b4) & ((e & 32) ? b5 : ~b5);
        unsigned long long mb =
            ((lane & 1)  ? b0 : ~b0) & ((lane & 2)  ? b1 : ~b1) &
            ((lane & 4)  ? b2 : ~b2) & ((lane & 8)  ? b3 : ~b3) &
            ((lane & 16) ? b4 : ~b4) & ((lane & 32) ? b5 : ~b5);

        int lr  = __popcll(my & ((1ULL << lane) - 1ULL));  // rank within batch
        int off = __shfl(cnt, e);                           // earlier batches, same expert
        localrank[base + j0 + lane] = off + lr;
        cnt += __popcll(mb);
    }
    hist[w][lane] = cnt;
    __syncthreads();

    if (tid < 64) {  // lane-per-expert exclusive scan over 16 chunks
        int off = 0;
        for (int w2 = 0; w2 < 16; ++w2) {
            chunkoff[w2][tid] = off;
            off += hist[w2][tid];
        }
    }
    __syncthreads();

    // Sparse scatter: at most one nonzero per token row in each output tensor.
    // Row s, expert t, rank r -> flat index s*(E*C) + t*C + r.
    for (int s = tid; s < NTOK; s += 1024) {
        int t = top1[s];
        int r = localrank[s] + chunkoff[s >> 9][t];
        if (r < CAP) {
            size_t idx = (size_t)s * (NEXP * CAP) + (size_t)(t * CAP + r);
            outc[idx] = val[s];
            outm[idx] = 1.0f;
        }
    }
}

extern "C" void kernel_launch(void* const* d_in, const int* in_sizes, int n_in,
                              void* d_out, int out_size, void* d_ws, size_t ws_size,
                              hipStream_t stream) {
    const float* in = (const float*)d_in[0];

    // workspace: top1[8192] int | val[8192] float
    int*   top1 = (int*)d_ws;
    float* val  = (float*)((char*)d_ws + NTOK * 4);

    float* outc = (float*)d_out;
    float* outm = outc + (size_t)SEC;

    hipLaunchKernelGGL(k_zero, dim3(ZWG), dim3(256), 0, stream, (v4f*)d_out);
    hipLaunchKernelGGL(k_top1, dim3(NTOK / 4), dim3(256), 0, stream, in, top1, val);
    hipLaunchKernelGGL(k_rank_scatter, dim3(1), dim3(1024), 0, stream,
                       top1, val, outc, outm);
}

// Round 6
// 1051.737 us; speedup vs baseline: 1.0428x; 1.0428x over previous
//
#include <hip/hip_runtime.h>
#include <math.h>

// Problem constants (S=8192 tokens, E=64 experts, capacity=256)
#define NTOK 8192
#define NEXP 64
#define CAP  256
#define SEC  (NTOK * NEXP * CAP)   // 134217728 floats per output tensor

typedef float v4f __attribute__((ext_vector_type(4)));

// ---------------------------------------------------------------------------
// Kernel 0: LOW-OCCUPANCY contiguous zero-fill of both output tensors (1 GiB).
// Key insight from the 6.2 TB/s rocclr reference dispatch: it runs at
// OccupancyPercent ~10% (~3 waves/CU), not a saturated grid. 6.2 TB/s only
// needs one 1 KiB wave-store per ~89 cyc/CU; few long sequential streams per
// CU preserve DRAM page locality, 32 interleaved streams/CU thrash it.
// 256 WGs (1/CU, 4 waves), each owns a contiguous 4 MiB chunk, x4-unrolled
// plain dwordx4 stores, zero loads.
// ---------------------------------------------------------------------------
#define ZWG 256
#define CHUNKV4 (SEC * 2 / 4 / ZWG)   // 262144 float4 per block (4 MiB)
__global__ __launch_bounds__(256) void k_zero(v4f* __restrict__ out) {
    v4f z = {0.0f, 0.0f, 0.0f, 0.0f};
    v4f* base = out + (size_t)blockIdx.x * CHUNKV4;
#pragma unroll 4
    for (int i = threadIdx.x; i < CHUNKV4; i += 256)
        base[i] = z;                  // plain global_store_dwordx4
}

// ---------------------------------------------------------------------------
// Kernel 1: per-token argmax (first-index tie-break) + softmax value at top1.
// One wave (64 lanes) per token row; lane e holds logit for expert e.
// ---------------------------------------------------------------------------
__global__ __launch_bounds__(256) void k_top1(const float* __restrict__ in,
                                              int* __restrict__ top1,
                                              float* __restrict__ val) {
    int wave = threadIdx.x >> 6;
    int lane = threadIdx.x & 63;
    int s = blockIdx.x * 4 + wave;
    float x = in[s * NEXP + lane];

    float bv = x;
    int   bi = lane;
#pragma unroll
    for (int off = 32; off > 0; off >>= 1) {
        float ov = __shfl_xor(bv, off);
        int   oi = __shfl_xor(bi, off);
        if (ov > bv || (ov == bv && oi < bi)) { bv = ov; bi = oi; }
    }
    float ex = expf(x - bv);
#pragma unroll
    for (int off = 32; off > 0; off >>= 1) ex += __shfl_xor(ex, off);

    if (lane == 0) {
        top1[s] = bi;
        val[s]  = 1.0f / ex;   // softmax value at the argmax
    }
}

// ---------------------------------------------------------------------------
// Kernel 2: deterministic per-expert exclusive rank via 6-ballot radix masks,
// fused with the sparse scatter (<=8192 nonzero (val, 1.0f) pairs, ~64 KiB).
// Single block, 16 waves; wave w owns tokens [w*512, w*512+512).
// ---------------------------------------------------------------------------
__global__ __launch_bounds__(1024) void k_rank_scatter(const int* __restrict__ top1,
                                                       const float* __restrict__ val,
                                                       float* __restrict__ outc,
                                                       float* __restrict__ outm) {
    __shared__ int localrank[NTOK];      // 32 KB
    __shared__ int hist[16][64];
    __shared__ int chunkoff[16][64];

    int tid  = threadIdx.x;
    int w    = tid >> 6;
    int lane = tid & 63;
    int base = w * 512;

    int cnt = 0;  // lane l: tokens so far in this chunk routed to expert l
    for (int j0 = 0; j0 < 512; j0 += 64) {
        int e = top1[base + j0 + lane];
        unsigned long long b0 = __ballot((e & 1)  != 0);
        unsigned long long b1 = __ballot((e & 2)  != 0);
        unsigned long long b2 = __ballot((e & 4)  != 0);
        unsigned long long b3 = __ballot((e & 8)  != 0);
        unsigned long long b4 = __ballot((e & 16) != 0);
        unsigned long long b5 = __ballot((e & 32) != 0);
        unsigned long long my =
            ((e & 1)  ? b0 : ~b0) & ((e & 2)  ? b1 : ~b1) &
            ((e & 4)  ? b2 : ~b2) & ((e & 8)  ? b3 : ~b3) &
            ((e & 16) ? b4 : ~b4) & ((e & 32) ? b5 : ~b5);
        unsigned long long mb =
            ((lane & 1)  ? b0 : ~b0) & ((lane & 2)  ? b1 : ~b1) &
            ((lane & 4)  ? b2 : ~b2) & ((lane & 8)  ? b3 : ~b3) &
            ((lane & 16) ? b4 : ~b4) & ((lane & 32) ? b5 : ~b5);

        int lr  = __popcll(my & ((1ULL << lane) - 1ULL));  // rank within batch
        int off = __shfl(cnt, e);                           // earlier batches, same expert
        localrank[base + j0 + lane] = off + lr;
        cnt += __popcll(mb);
    }
    hist[w][lane] = cnt;
    __syncthreads();

    if (tid < 64) {  // lane-per-expert exclusive scan over 16 chunks
        int off = 0;
        for (int w2 = 0; w2 < 16; ++w2) {
            chunkoff[w2][tid] = off;
            off += hist[w2][tid];
        }
    }
    __syncthreads();

    // Sparse scatter: at most one nonzero per token row in each output tensor.
    // Row s, expert t, rank r -> flat index s*(E*C) + t*C + r.
    for (int s = tid; s < NTOK; s += 1024) {
        int t = top1[s];
        int r = localrank[s] + chunkoff[s >> 9][t];
        if (r < CAP) {
            size_t idx = (size_t)s * (NEXP * CAP) + (size_t)(t * CAP + r);
            outc[idx] = val[s];
            outm[idx] = 1.0f;
        }
    }
}

extern "C" void kernel_launch(void* const* d_in, const int* in_sizes, int n_in,
                              void* d_out, int out_size, void* d_ws, size_t ws_size,
                              hipStream_t stream) {
    const float* in = (const float*)d_in[0];

    // workspace: top1[8192] int | val[8192] float
    int*   top1 = (int*)d_ws;
    float* val  = (float*)((char*)d_ws + NTOK * 4);

    float* outc = (float*)d_out;
    float* outm = outc + (size_t)SEC;

    hipLaunchKernelGGL(k_zero, dim3(ZWG), dim3(256), 0, stream, (v4f*)d_out);
    hipLaunchKernelGGL(k_top1, dim3(NTOK / 4), dim3(256), 0, stream, in, top1, val);
    hipLaunchKernelGGL(k_rank_scatter, dim3(1), dim3(1024), 0, stream,
                       top1, val, outc, outm);
}

// Round 7
// 1007.127 us; speedup vs baseline: 1.0889x; 1.0443x over previous
//
#include <hip/hip_runtime.h>
#include <math.h>

// Problem constants (S=8192 tokens, E=64 experts, capacity=256)
#define NTOK 8192
#define NEXP 64
#define CAP  256
#define SEC  (NTOK * NEXP * CAP)   // 134217728 floats per output tensor

typedef float v4f __attribute__((ext_vector_type(4)));

// ---------------------------------------------------------------------------
// Kernel 1: per-token argmax (first-index tie-break) + softmax value at top1.
// One wave (64 lanes) per token row; lane e holds logit for expert e.
// ---------------------------------------------------------------------------
__global__ __launch_bounds__(256) void k_top1(const float* __restrict__ in,
                                              int* __restrict__ top1,
                                              float* __restrict__ val) {
    int wave = threadIdx.x >> 6;
    int lane = threadIdx.x & 63;
    int s = blockIdx.x * 4 + wave;
    float x = in[s * NEXP + lane];

    float bv = x;
    int   bi = lane;
#pragma unroll
    for (int off = 32; off > 0; off >>= 1) {
        float ov = __shfl_xor(bv, off);
        int   oi = __shfl_xor(bi, off);
        if (ov > bv || (ov == bv && oi < bi)) { bv = ov; bi = oi; }
    }
    float ex = expf(x - bv);
#pragma unroll
    for (int off = 32; off > 0; off >>= 1) ex += __shfl_xor(ex, off);

    if (lane == 0) {
        top1[s] = bi;
        val[s]  = 1.0f / ex;   // softmax value at the argmax
    }
}

// ---------------------------------------------------------------------------
// Kernel 2: deterministic per-expert exclusive rank via 6-ballot radix masks.
// Single block, 16 waves; wave w owns tokens [w*512, w*512+512).
// Emits packed rowinfo: {pos = t*CAP + rank (or -1 if dropped), bits(val)}.
// ---------------------------------------------------------------------------
__global__ __launch_bounds__(1024) void k_rank(const int* __restrict__ top1,
                                               const float* __restrict__ val,
                                               int2* __restrict__ rowinfo) {
    __shared__ int localrank[NTOK];      // 32 KB
    __shared__ int hist[16][64];
    __shared__ int chunkoff[16][64];

    int tid  = threadIdx.x;
    int w    = tid >> 6;
    int lane = tid & 63;
    int base = w * 512;

    int cnt = 0;  // lane l: tokens so far in this chunk routed to expert l
    for (int j0 = 0; j0 < 512; j0 += 64) {
        int e = top1[base + j0 + lane];
        unsigned long long b0 = __ballot((e & 1)  != 0);
        unsigned long long b1 = __ballot((e & 2)  != 0);
        unsigned long long b2 = __ballot((e & 4)  != 0);
        unsigned long long b3 = __ballot((e & 8)  != 0);
        unsigned long long b4 = __ballot((e & 16) != 0);
        unsigned long long b5 = __ballot((e & 32) != 0);
        unsigned long long my =
            ((e & 1)  ? b0 : ~b0) & ((e & 2)  ? b1 : ~b1) &
            ((e & 4)  ? b2 : ~b2) & ((e & 8)  ? b3 : ~b3) &
            ((e & 16) ? b4 : ~b4) & ((e & 32) ? b5 : ~b5);
        unsigned long long mb =
            ((lane & 1)  ? b0 : ~b0) & ((lane & 2)  ? b1 : ~b1) &
            ((lane & 4)  ? b2 : ~b2) & ((lane & 8)  ? b3 : ~b3) &
            ((lane & 16) ? b4 : ~b4) & ((lane & 32) ? b5 : ~b5);

        int lr  = __popcll(my & ((1ULL << lane) - 1ULL));  // rank within batch
        int off = __shfl(cnt, e);                           // earlier batches, same expert
        localrank[base + j0 + lane] = off + lr;
        cnt += __popcll(mb);
    }
    hist[w][lane] = cnt;
    __syncthreads();

    if (tid < 64) {  // lane-per-expert exclusive scan over 16 chunks
        int off = 0;
        for (int w2 = 0; w2 < 16; ++w2) {
            chunkoff[w2][tid] = off;
            off += hist[w2][tid];
        }
    }
    __syncthreads();

    for (int s = tid; s < NTOK; s += 1024) {
        int t = top1[s];
        int r = localrank[s] + chunkoff[s >> 9][t];
        int pos = (r < CAP) ? (t * CAP + r) : -1;   // -1: dropped token, row all-zero
        rowinfo[s] = make_int2(pos, __float_as_int(val[s]));
    }
}

// ---------------------------------------------------------------------------
// Kernel 3: fused zero-fill + scatter, STREAM-SPLIT variant (best measured:
// 1011 us total, R3). nt stores, one dwordx4 per thread, each wave writes
// exactly ONE contiguous stream: blocks [0, half) cover outc, blocks
// [half, 2*half) cover outm. Six alternative store shapes (plain stores,
// capped grid-stride, compact many-per-thread, low-occupancy 1 WG/CU,
// memset node, interleaved dual-stream) all measured 1033-1097 us -- the
// write-rate cap inside the timed window is environmental (poison-fill
// traffic), not store-shape-structural.
// ---------------------------------------------------------------------------
__global__ __launch_bounds__(256) void k_fill(const int2* __restrict__ rowinfo,
                                              v4f* __restrict__ outc,
                                              v4f* __restrict__ outm) {
    const int half = SEC / 4 / 256;             // 131072 blocks per tensor
    bool isC = (int)blockIdx.x < half;
    int  b   = isC ? blockIdx.x : blockIdx.x - half;
    int gid = b * 256 + threadIdx.x;            // float4 index, < SEC/4
    int s = gid >> 12;                          // 4096 float4 per row
    int q = (gid & 4095) << 2;                  // float offset of this float4 in row

    int2 ri = rowinfo[s];                       // wave-uniform -> scalar broadcast load
    float v = isC ? __int_as_float(ri.y) : 1.0f;
    int d = ri.x - q;                           // nonzero at this float4 iff d in [0,4)

    v4f o;
    o.x = (d == 0) ? v : 0.0f;
    o.y = (d == 1) ? v : 0.0f;
    o.z = (d == 2) ? v : 0.0f;
    o.w = (d == 3) ? v : 0.0f;

    v4f* out = isC ? outc : outm;
    __builtin_nontemporal_store(o, &out[gid]);
}

extern "C" void kernel_launch(void* const* d_in, const int* in_sizes, int n_in,
                              void* d_out, int out_size, void* d_ws, size_t ws_size,
                              hipStream_t stream) {
    const float* in = (const float*)d_in[0];

    // workspace: top1[8192] int | val[8192] float | rowinfo[8192] int2
    int*   top1    = (int*)d_ws;
    float* val     = (float*)((char*)d_ws + NTOK * 4);
    int2*  rowinfo = (int2*)((char*)d_ws + NTOK * 8);

    float* outc = (float*)d_out;
    float* outm = outc + (size_t)SEC;

    hipLaunchKernelGGL(k_top1, dim3(NTOK / 4), dim3(256), 0, stream, in, top1, val);
    hipLaunchKernelGGL(k_rank, dim3(1), dim3(1024), 0, stream, top1, val, rowinfo);
    hipLaunchKernelGGL(k_fill, dim3(SEC / 4 / 256 * 2), dim3(256), 0, stream,
                       rowinfo, (v4f*)outc, (v4f*)outm);
}